// Round 6
// baseline (51.395 us; speedup 1.0000x reference)
//
#include <hip/hip_runtime.h>
#include <math.h>

#define NH 8            // heads
#define HD 32           // head dim
#define MD 128          // max dist
#define NW 257          // 2*MD+1
#define NWP 272         // padded to 17*16
#define WSM 64          // smoothed PE width
#define NB 4            // batch
#define NL 2048         // length
#define NC 64           // channels
#define NHD 256         // NH*HD
#define PR 8            // rows per proj block
#define NPROJ_BLK (NB * NL / PR)   // 1024
#define SPE_BLK 34                 // 34*256*8 == NH*NWP*HD
#define SCALE 0.17677669529663687f // 32^-0.5

using bf16x8 = __attribute__((ext_vector_type(8))) short;
using f32x4  = __attribute__((ext_vector_type(4))) float;
using i32x4  = __attribute__((ext_vector_type(4))) int;

__device__ __forceinline__ unsigned short f2bf(float f) {
  unsigned int u = __builtin_bit_cast(unsigned int, f);
  u = (u + 0x7fffu + ((u >> 16) & 1u)) >> 16;
  return (unsigned short)u;
}

// ---- projections (qu=q+u_pe, qv=q+v_pe, k*scale as bf16; v=sigmoid f32)
// ---- + trailing blocks: smooth-PE (pre-scaled) and d_out zeroing (replaces memset dispatch)
__global__ __launch_bounds__(256) void proj_spe_kernel(
    const float* __restrict__ x,
    const float* __restrict__ Wq, const float* __restrict__ bq,
    const float* __restrict__ Wk, const float* __restrict__ bk,
    const float* __restrict__ Wv, const float* __restrict__ dpe,
    const float* __restrict__ u_pe, const float* __restrict__ v_pe,
    unsigned short* __restrict__ qu, unsigned short* __restrict__ qv,
    unsigned short* __restrict__ kb, float* __restrict__ vv,
    unsigned short* __restrict__ spt, float* __restrict__ out) {
  const int t = threadIdx.x;

  if (blockIdx.x >= NPROJ_BLK) {
    const int base = (blockIdx.x - NPROJ_BLK) * 256 + t;
    // zero the output accumulator (band kernel atomically adds; stream order protects us)
    if (base < NB * NW * NH) out[base] = 0.f;
    // smooth_pe bilinear upsample -> bf16 [h][272][32], pre-scaled, rows 257..271 zeroed
    for (int idx = base; idx < NH * NWP * HD; idx += SPE_BLK * 256) {
      const int d = idx & 31;
      const int hm = idx >> 5;
      const int m = hm % NWP;
      const int h = hm / NWP;
      float val = 0.f;
      if (m < NW) {
        float tt = (m + 0.5f) * ((float)WSM / (float)NW) - 0.5f;
        tt = fminf(fmaxf(tt, 0.f), (float)(WSM - 1));
        const int i0 = (int)tt;
        const float f = tt - (float)i0;
        const int i1 = (i0 + 1 < WSM) ? i0 + 1 : WSM - 1;
        const float* bse = dpe + ((size_t)h * HD + d) * WSM;
        val = (bse[i0] * (1.f - f) + bse[i1] * f) * SCALE;
      }
      spt[idx] = f2bf(val);
    }
    return;
  }

  __shared__ float xs[PR][NC];
  const int row0 = blockIdx.x * PR;
  if (t < PR * NC / 4)
    reinterpret_cast<float4*>(xs)[t] = reinterpret_cast<const float4*>(x + (size_t)row0 * NC)[t];
  __syncthreads();

  const int h = t >> 5, d = t & 31;
  const float uu = u_pe[t];   // (H,1,1,D) flat == h*32+d == t
  const float vp = v_pe[t];
  float accq[PR], acck[PR];
  const float bq_t = bq[t], bk_t = bk[t];
#pragma unroll
  for (int r = 0; r < PR; ++r) { accq[r] = bq_t; acck[r] = bk_t; }
#pragma unroll
  for (int c4 = 0; c4 < NC / 4; ++c4) {
    float wq4[4], wk4[4];
#pragma unroll
    for (int j = 0; j < 4; ++j) {
      wq4[j] = Wq[(4 * c4 + j) * NHD + t];
      wk4[j] = Wk[(4 * c4 + j) * NHD + t];
    }
#pragma unroll
    for (int r = 0; r < PR; ++r) {
      const float4 xv = *reinterpret_cast<const float4*>(&xs[r][4 * c4]);
      accq[r] = fmaf(xv.x, wq4[0], accq[r]);
      accq[r] = fmaf(xv.y, wq4[1], accq[r]);
      accq[r] = fmaf(xv.z, wq4[2], accq[r]);
      accq[r] = fmaf(xv.w, wq4[3], accq[r]);
      acck[r] = fmaf(xv.x, wk4[0], acck[r]);
      acck[r] = fmaf(xv.y, wk4[1], acck[r]);
      acck[r] = fmaf(xv.z, wk4[2], acck[r]);
      acck[r] = fmaf(xv.w, wk4[3], acck[r]);
    }
  }
#pragma unroll
  for (int r = 0; r < PR; ++r) {
    const int row = row0 + r;
    const int b = row >> 11, l = row & (NL - 1);
    const size_t o = (((size_t)h * NB + b) * NL + l) * HD + d;
    qu[o] = f2bf(accq[r] + uu);
    qv[o] = f2bf(accq[r] + vp);
    kb[o] = f2bf(acck[r] * SCALE);   // fold softmax scale into k
  }
  if (t < PR * NH) {
    const int r = t >> 3, hh = t & 7;
    float a = 0.f;
#pragma unroll
    for (int c4 = 0; c4 < NC / 4; ++c4) {
      const float4 xv = *reinterpret_cast<const float4*>(&xs[r][4 * c4]);
      a = fmaf(xv.x, Wv[(4 * c4 + 0) * NH + hh], a);
      a = fmaf(xv.y, Wv[(4 * c4 + 1) * NH + hh], a);
      a = fmaf(xv.z, Wv[(4 * c4 + 2) * NH + hh], a);
      a = fmaf(xv.w, Wv[(4 * c4 + 3) * NH + hh], a);
    }
    const int row = row0 + r;
    const int b = row >> 11, l = row & (NL - 1);
    vv[((size_t)hh * NB + b) * NL + l] = 1.f / (1.f + __expf(-a));
  }
}

// ---------- main: all-global MFMA band+PE pipeline (L1/L2-resident operands),
// ---------- no-max softmax, gate, reduce. LDS only for the tiny cross-wave buffer.
__global__ __launch_bounds__(256, 4) void band_attn_mfma(
    const unsigned short* __restrict__ qu, const unsigned short* __restrict__ qv,
    const unsigned short* __restrict__ kb, const float* __restrict__ vv,
    const unsigned short* __restrict__ spt, float* __restrict__ out) {
  __shared__ float red[4 * NWP];      // 4.25 KB -> occupancy is VGPR-bound, not LDS-bound

  const int bid = blockIdx.x;
  const int tile = bid & 31;
  const int hb = bid >> 5;            // h*NB + b
  const int b = hb & (NB - 1);
  const int h = hb >> 2;
  const int n0 = tile << 6;
  const int jlo = NL - 64 - n0;       // k rows jlo..jlo+63 (i ascending)
  const int tid = threadIdx.x;
  const int l = tid & 63;
  const int w = tid >> 6;             // wave: rows i = 16w..16w+15
  const int c = l & 15;               // fragment row/col index
  const int g = l >> 4;               // k-chunk group
  const int g8 = g * 8;               // element offset of the 16B chunk

  const unsigned short* qu_h = qu + (size_t)hb * NL * HD;
  const unsigned short* qv_h = qv + (size_t)hb * NL * HD;
  const unsigned short* k_h  = kb + (size_t)hb * NL * HD;
  const unsigned short* sp_h = spt + (size_t)h * NWP * HD;  // pre-scaled
  const float* vv_h = vv + (size_t)hb * NL;

  // A fragments + v-gate: direct global (L2-hot after proj).
  const bf16x8 ak  = *reinterpret_cast<const bf16x8*>(k_h  + (size_t)(jlo + 16 * w + c) * HD + g8);
  const bf16x8 aqv = *reinterpret_cast<const bf16x8*>(qv_h + (size_t)(n0 + 63 - 16 * w - c) * HD + g8);
  const f32x4 v4 = *reinterpret_cast<const f32x4*>(vv_h + (n0 + 60 - 16 * w - 4 * g));

  const f32x4 z4 = {0.f, 0.f, 0.f, 0.f};

  // realign constants: C/D layout row=(l>>4)*4+reg, col=l&15 (m89-verified);
  // source col = (4g+r-c)&15 (tile-independent), pick tile 16-t vs 15-t by cond.
  int sl[4]; bool cond[4];
#pragma unroll
  for (int r = 0; r < 4; ++r) {
    sl[r] = 16 * g + ((4 * g + r - c) & 15);
    cond[r] = (4 * g + r) >= c;
  }

  const int wq0 = jlo - MD + 16 * w;  // first window row for this wave (may be <0)
  f32x4 s[17];
  f32x4 shp;
  // Fused pipeline: step U computes PE tile t=16-U and band tile T=U, finalizes s[16-U].
  // All B-fragments direct from global: 17 sp rows (identical across the 4 waves -> L1
  // broadcast) + 17 qu window rows (20 KB window -> L1-fit); loads are independent and
  // unrolled so they batch-issue and overlap with MFMA.
#pragma unroll
  for (int U = 0; U <= 16; ++U) {
    const int tpe = 16 - U;
    const bf16x8 bsp = *reinterpret_cast<const bf16x8*>(sp_h + (size_t)(16 * tpe + c) * HD + g8);
    const f32x4 spe = __builtin_amdgcn_mfma_f32_16x16x32_bf16(aqv, bsp, z4, 0, 0, 0);

    const int grow = wq0 + 16 * U + c;
    i32x4 raw = {0, 0, 0, 0};
    if ((unsigned)grow < (unsigned)NL)
      raw = *reinterpret_cast<const i32x4*>(qu_h + (size_t)grow * HD + g8);
    const f32x4 c1 = __builtin_amdgcn_mfma_f32_16x16x32_bf16(ak, __builtin_bit_cast(bf16x8, raw), z4, 0, 0, 0);

    f32x4 shc;
#pragma unroll
    for (int r = 0; r < 4; ++r) shc[r] = __shfl(c1[r], sl[r], 64);

    if (U == 0) {
#pragma unroll
      for (int r = 0; r < 4; ++r)
        s[16][r] = (c == 0) ? (shc[r] + spe[r]) : -1e30f;  // m=256+c valid only c==0
    } else {
#pragma unroll
      for (int r = 0; r < 4; ++r) {
        const float band = cond[r] ? shc[r] : shp[r];
        s[tpe][r] = band + spe[r];
      }
    }
    shp = shc;
  }

  // per-row softmax, NO max-subtraction: |s| <~ 1 here, exp is safe in f32 and
  // p/sum is mathematically identical. No serial fmax chain.
  float wgt[4];
#pragma unroll
  for (int r = 0; r < 4; ++r) {
    float sum = 0.f;
#pragma unroll
    for (int t = 0; t < 17; ++t) {
      const float p = __expf(s[t][r]);
      s[t][r] = p;
      sum += p;
    }
#pragma unroll
    for (int off = 1; off < 16; off <<= 1) sum += __shfl_xor(sum, off, 16);
    wgt[r] = v4[3 - r] / sum;   // v[n], n = n0+63-(16w+4g+r)
  }

  // out[m] += sum_i p * w : regs -> cross-group -> cross-wave (LDS) -> atomics
#pragma unroll
  for (int t = 0; t < 17; ++t) {
    float y = s[t][0] * wgt[0] + s[t][1] * wgt[1] + s[t][2] * wgt[2] + s[t][3] * wgt[3];
    y += __shfl_xor(y, 16, 64);
    y += __shfl_xor(y, 32, 64);
    if (l < 16) red[w * NWP + 16 * t + c] = y;
  }
  __syncthreads();
  for (int m = tid; m < NW; m += 256) {
    const float ssum = red[m] + red[NWP + m] + red[2 * NWP + m] + red[3 * NWP + m];
    atomicAdd(&out[((size_t)b * NW + m) * NH + h], ssum);
  }
}

extern "C" void kernel_launch(void* const* d_in, const int* in_sizes, int n_in,
                              void* d_out, int out_size, void* d_ws, size_t ws_size,
                              hipStream_t stream) {
  const float* x = (const float*)d_in[0];
  const float* Wq = (const float*)d_in[1];
  const float* bq = (const float*)d_in[2];
  const float* Wk = (const float*)d_in[3];
  const float* bk = (const float*)d_in[4];
  const float* Wv = (const float*)d_in[5];
  const float* dpe = (const float*)d_in[6];
  const float* u_pe = (const float*)d_in[7];
  const float* v_pe = (const float*)d_in[8];
  float* out = (float*)d_out;

  const size_t qk_elems = (size_t)NH * NB * NL * HD;  // 2,097,152
  float* vv = (float*)d_ws;                           // 65,536 f32
  unsigned short* qu = (unsigned short*)(vv + (size_t)NH * NB * NL);
  unsigned short* qv = qu + qk_elems;
  unsigned short* kb = qv + qk_elems;
  unsigned short* spt = kb + qk_elems;                // 8*272*32

  hipLaunchKernelGGL(proj_spe_kernel, dim3(NPROJ_BLK + SPE_BLK), dim3(256), 0, stream,
                     x, Wq, bq, Wk, bk, Wv, dpe, u_pe, v_pe, qu, qv, kb, vv, spt, out);
  hipLaunchKernelGGL(band_attn_mfma, dim3(NH * NB * 32), dim3(256), 0, stream,
                     qu, qv, kb, vv, spt, out);
}

// Round 7
// 46.725 us; speedup vs baseline: 1.1000x; 1.1000x over previous
//
#include <hip/hip_runtime.h>
#include <math.h>

#define NH 8            // heads
#define HD 32           // head dim
#define MD 128          // max dist
#define NW 257          // 2*MD+1
#define NWP 272         // padded to 17*16
#define WSM 64          // smoothed PE width
#define NB 4            // batch
#define NL 2048         // length
#define NC 64           // channels
#define NHD 256         // NH*HD
#define PR 8            // rows per proj block
#define NPROJ_BLK (NB * NL / PR)   // 1024
#define SPE_BLK 34                 // 34*256*8 == NH*NWP*HD
#define SP 40           // padded LDS row stride in bf16 elems (80B)
// 32^-0.5 * log2(e): scores land in log2 domain -> exp2f directly
#define SC2 0.2550928063161107f

using bf16x8 = __attribute__((ext_vector_type(8))) short;
using f32x4  = __attribute__((ext_vector_type(4))) float;
using i32x4  = __attribute__((ext_vector_type(4))) int;

__device__ __forceinline__ unsigned short f2bf(float f) {
  unsigned int u = __builtin_bit_cast(unsigned int, f);
  u = (u + 0x7fffu + ((u >> 16) & 1u)) >> 16;
  return (unsigned short)u;
}

// ---- projections (qu=q+u_pe, qv=q+v_pe, k*SC2 as bf16; v=sigmoid f32)
// ---- + trailing blocks: smooth-PE (pre-scaled by SC2) and d_out zeroing
__global__ __launch_bounds__(256) void proj_spe_kernel(
    const float* __restrict__ x,
    const float* __restrict__ Wq, const float* __restrict__ bq,
    const float* __restrict__ Wk, const float* __restrict__ bk,
    const float* __restrict__ Wv, const float* __restrict__ dpe,
    const float* __restrict__ u_pe, const float* __restrict__ v_pe,
    unsigned short* __restrict__ qu, unsigned short* __restrict__ qv,
    unsigned short* __restrict__ kb, float* __restrict__ vv,
    unsigned short* __restrict__ spt, float* __restrict__ out) {
  const int t = threadIdx.x;

  if (blockIdx.x >= NPROJ_BLK) {
    const int base = (blockIdx.x - NPROJ_BLK) * 256 + t;
    // zero the output accumulator (band kernel atomically adds; stream order protects us)
    if (base < NB * NW * NH) out[base] = 0.f;
    // smooth_pe bilinear upsample -> bf16 [h][272][32], pre-scaled, rows 257..271 zeroed
    for (int idx = base; idx < NH * NWP * HD; idx += SPE_BLK * 256) {
      const int d = idx & 31;
      const int hm = idx >> 5;
      const int m = hm % NWP;
      const int h = hm / NWP;
      float val = 0.f;
      if (m < NW) {
        float tt = (m + 0.5f) * ((float)WSM / (float)NW) - 0.5f;
        tt = fminf(fmaxf(tt, 0.f), (float)(WSM - 1));
        const int i0 = (int)tt;
        const float f = tt - (float)i0;
        const int i1 = (i0 + 1 < WSM) ? i0 + 1 : WSM - 1;
        const float* bse = dpe + ((size_t)h * HD + d) * WSM;
        val = (bse[i0] * (1.f - f) + bse[i1] * f) * SC2;
      }
      spt[idx] = f2bf(val);
    }
    return;
  }

  __shared__ float xs[PR][NC];
  const int row0 = blockIdx.x * PR;
  if (t < PR * NC / 4)
    reinterpret_cast<float4*>(xs)[t] = reinterpret_cast<const float4*>(x + (size_t)row0 * NC)[t];
  __syncthreads();

  const int h = t >> 5, d = t & 31;
  const float uu = u_pe[t];   // (H,1,1,D) flat == h*32+d == t
  const float vp = v_pe[t];
  float accq[PR], acck[PR];
  const float bq_t = bq[t], bk_t = bk[t];
#pragma unroll
  for (int r = 0; r < PR; ++r) { accq[r] = bq_t; acck[r] = bk_t; }
#pragma unroll
  for (int c4 = 0; c4 < NC / 4; ++c4) {
    float wq4[4], wk4[4];
#pragma unroll
    for (int j = 0; j < 4; ++j) {
      wq4[j] = Wq[(4 * c4 + j) * NHD + t];
      wk4[j] = Wk[(4 * c4 + j) * NHD + t];
    }
#pragma unroll
    for (int r = 0; r < PR; ++r) {
      const float4 xv = *reinterpret_cast<const float4*>(&xs[r][4 * c4]);
      accq[r] = fmaf(xv.x, wq4[0], accq[r]);
      accq[r] = fmaf(xv.y, wq4[1], accq[r]);
      accq[r] = fmaf(xv.z, wq4[2], accq[r]);
      accq[r] = fmaf(xv.w, wq4[3], accq[r]);
      acck[r] = fmaf(xv.x, wk4[0], acck[r]);
      acck[r] = fmaf(xv.y, wk4[1], acck[r]);
      acck[r] = fmaf(xv.z, wk4[2], acck[r]);
      acck[r] = fmaf(xv.w, wk4[3], acck[r]);
    }
  }
#pragma unroll
  for (int r = 0; r < PR; ++r) {
    const int row = row0 + r;
    const int b = row >> 11, l = row & (NL - 1);
    const size_t o = (((size_t)h * NB + b) * NL + l) * HD + d;
    qu[o] = f2bf(accq[r] + uu);
    qv[o] = f2bf(accq[r] + vp);
    kb[o] = f2bf(acck[r] * SC2);   // softmax scale * log2e folded into k
  }
  if (t < PR * NH) {
    const int r = t >> 3, hh = t & 7;
    float a = 0.f;
#pragma unroll
    for (int c4 = 0; c4 < NC / 4; ++c4) {
      const float4 xv = *reinterpret_cast<const float4*>(&xs[r][4 * c4]);
      a = fmaf(xv.x, Wv[(4 * c4 + 0) * NH + hh], a);
      a = fmaf(xv.y, Wv[(4 * c4 + 1) * NH + hh], a);
      a = fmaf(xv.z, Wv[(4 * c4 + 2) * NH + hh], a);
      a = fmaf(xv.w, Wv[(4 * c4 + 3) * NH + hh], a);
    }
    const int row = row0 + r;
    const int b = row >> 11, l = row & (NL - 1);
    vv[((size_t)hh * NB + b) * NL + l] = 1.f / (1.f + __expf(-a));
  }
}

// ---------- main: LDS-staged MFMA band+PE pipeline (batched load-then-write staging),
// ---------- no-max exp2 softmax, gate, reduce ----------
__global__ __launch_bounds__(256, 4) void band_attn_mfma(
    const unsigned short* __restrict__ qu, const unsigned short* __restrict__ qv,
    const unsigned short* __restrict__ kb, const float* __restrict__ vv,
    const unsigned short* __restrict__ spt, float* __restrict__ out) {
  __shared__ __align__(16) unsigned short qu_sh[320 * SP];  // qu window, stride-40 padded
  __shared__ __align__(16) unsigned short sp_sh[NWP * SP];  // smooth-PE head table (pre-scaled)
  float* red = reinterpret_cast<float*>(qu_sh);             // overlay after barrier

  const int bid = blockIdx.x;
  const int tile = bid & 31;
  const int hb = bid >> 5;            // h*NB + b
  const int b = hb & (NB - 1);
  const int h = hb >> 2;
  const int n0 = tile << 6;
  const int jlo = NL - 64 - n0;       // k rows jlo..jlo+63 (i ascending)
  const int tid = threadIdx.x;
  const int l = tid & 63;
  const int w = tid >> 6;             // wave: rows i = 16w..16w+15
  const int c = l & 15;               // fragment row/col index
  const int g = l >> 4;               // k-chunk group
  const int g8 = g * 8;               // element offset of the 16B chunk

  const unsigned short* qu_h = qu + (size_t)hb * NL * HD;
  const unsigned short* qv_h = qv + (size_t)hb * NL * HD;
  const unsigned short* k_h  = kb + (size_t)hb * NL * HD;
  const unsigned short* sp_h = spt + (size_t)h * NWP * HD;
  const float* vv_h = vv + (size_t)hb * NL;

  // A fragments + v-gate direct from global, issued BEFORE staging (latency hides under it).
  const bf16x8 ak  = *reinterpret_cast<const bf16x8*>(k_h  + (size_t)(jlo + 16 * w + c) * HD + g8);
  const bf16x8 aqv = *reinterpret_cast<const bf16x8*>(qv_h + (size_t)(n0 + 63 - 16 * w - c) * HD + g8);
  const f32x4 v4 = *reinterpret_cast<const f32x4*>(vv_h + (n0 + 60 - 16 * w - 4 * g));

  // ---- staging, batched: ALL global loads issued into regs, THEN all ds_writes.
  // qu window: 320 rows x 4 chunks = 1280; sp table: 272 x 4 = 1088. 256 threads.
  const int wq0_blk = jlo - MD;       // global row of qu_sh row 0 (may be <0)
  i32x4 stq[5], stp[5];
#pragma unroll
  for (int it = 0; it < 5; ++it) {
    const int p = tid + it * 256;
    const int gr = wq0_blk + (p >> 2);
    i32x4 val = {0, 0, 0, 0};
    if ((unsigned)gr < (unsigned)NL)
      val = *reinterpret_cast<const i32x4*>(qu_h + (size_t)gr * HD + (p & 3) * 8);
    stq[it] = val;
  }
#pragma unroll
  for (int it = 0; it < 5; ++it) {
    const int p = tid + it * 256;
    i32x4 val = {0, 0, 0, 0};
    if (it < 4 || p < NWP * 4)
      val = *reinterpret_cast<const i32x4*>(sp_h + (size_t)(p >> 2) * HD + (p & 3) * 8);
    stp[it] = val;
  }
#pragma unroll
  for (int it = 0; it < 5; ++it) {
    const int p = tid + it * 256;
    *reinterpret_cast<i32x4*>(&qu_sh[(p >> 2) * SP + (p & 3) * 8]) = stq[it];
  }
#pragma unroll
  for (int it = 0; it < 5; ++it) {
    const int p = tid + it * 256;
    if (it < 4 || p < NWP * 4)
      *reinterpret_cast<i32x4*>(&sp_sh[(p >> 2) * SP + (p & 3) * 8]) = stp[it];
  }
  __syncthreads();

  const f32x4 z4 = {0.f, 0.f, 0.f, 0.f};

  // realign constants: C/D layout row=(l>>4)*4+reg, col=l&15 (m89-verified);
  // source col = (4g+r-c)&15 (tile-independent), pick tile 16-t vs 15-t by cond.
  int sl[4]; bool cond[4];
#pragma unroll
  for (int r = 0; r < 4; ++r) {
    sl[r] = 16 * g + ((4 * g + r - c) & 15);
    cond[r] = (4 * g + r) >= c;
  }

  f32x4 s[17];
  f32x4 shp;
  // Fused pipeline: step U computes PE tile t=16-U and band tile T=U, finalizes s[16-U].
  // kb and spt are pre-scaled by 32^-0.5*log2e, so s is the log2-domain score directly.
#pragma unroll
  for (int U = 0; U <= 16; ++U) {
    const int tpe = 16 - U;
    const bf16x8 bsp = *reinterpret_cast<const bf16x8*>(&sp_sh[(16 * tpe + c) * SP + g8]);
    const f32x4 spe = __builtin_amdgcn_mfma_f32_16x16x32_bf16(aqv, bsp, z4, 0, 0, 0);

    const bf16x8 bqu = *reinterpret_cast<const bf16x8*>(&qu_sh[(16 * w + 16 * U + c) * SP + g8]);
    const f32x4 c1 = __builtin_amdgcn_mfma_f32_16x16x32_bf16(ak, bqu, z4, 0, 0, 0);

    f32x4 shc;
#pragma unroll
    for (int r = 0; r < 4; ++r) shc[r] = __shfl(c1[r], sl[r], 64);

    if (U == 0) {
#pragma unroll
      for (int r = 0; r < 4; ++r)
        s[16][r] = (c == 0) ? (shc[r] + spe[r]) : -1e30f;  // m=256+c valid only c==0
    } else {
#pragma unroll
      for (int r = 0; r < 4; ++r) {
        const float band = cond[r] ? shc[r] : shp[r];
        s[tpe][r] = band + spe[r];
      }
    }
    shp = shc;
  }

  // per-row softmax, NO max-subtraction (|scores| ~ 1, exact in f32), exp2 domain.
  float wgt[4];
#pragma unroll
  for (int r = 0; r < 4; ++r) {
    float sum = 0.f;
#pragma unroll
    for (int t = 0; t < 17; ++t) {
      const float p = exp2f(s[t][r]);
      s[t][r] = p;
      sum += p;
    }
#pragma unroll
    for (int off = 1; off < 16; off <<= 1) sum += __shfl_xor(sum, off, 16);
    wgt[r] = v4[3 - r] / sum;   // v[n], n = n0+63-(16w+4g+r)
  }

  // out[m] += sum_i p * w : regs -> cross-group -> cross-wave (LDS) -> atomics
  __syncthreads();  // all waves done reading qu_sh; reuse as reduction buffer
#pragma unroll
  for (int t = 0; t < 17; ++t) {
    float y = s[t][0] * wgt[0] + s[t][1] * wgt[1] + s[t][2] * wgt[2] + s[t][3] * wgt[3];
    y += __shfl_xor(y, 16, 64);
    y += __shfl_xor(y, 32, 64);
    if (l < 16) red[w * NWP + 16 * t + c] = y;
  }
  __syncthreads();
  for (int m = tid; m < NW; m += 256) {
    const float ssum = red[m] + red[NWP + m] + red[2 * NWP + m] + red[3 * NWP + m];
    atomicAdd(&out[((size_t)b * NW + m) * NH + h], ssum);
  }
}

extern "C" void kernel_launch(void* const* d_in, const int* in_sizes, int n_in,
                              void* d_out, int out_size, void* d_ws, size_t ws_size,
                              hipStream_t stream) {
  const float* x = (const float*)d_in[0];
  const float* Wq = (const float*)d_in[1];
  const float* bq = (const float*)d_in[2];
  const float* Wk = (const float*)d_in[3];
  const float* bk = (const float*)d_in[4];
  const float* Wv = (const float*)d_in[5];
  const float* dpe = (const float*)d_in[6];
  const float* u_pe = (const float*)d_in[7];
  const float* v_pe = (const float*)d_in[8];
  float* out = (float*)d_out;

  const size_t qk_elems = (size_t)NH * NB * NL * HD;  // 2,097,152
  float* vv = (float*)d_ws;                           // 65,536 f32
  unsigned short* qu = (unsigned short*)(vv + (size_t)NH * NB * NL);
  unsigned short* qv = qu + qk_elems;
  unsigned short* kb = qv + qk_elems;
  unsigned short* spt = kb + qk_elems;                // 8*272*32

  hipLaunchKernelGGL(proj_spe_kernel, dim3(NPROJ_BLK + SPE_BLK), dim3(256), 0, stream,
                     x, Wq, bq, Wk, bk, Wv, dpe, u_pe, v_pe, qu, qv, kb, vv, spt, out);
  hipLaunchKernelGGL(band_attn_mfma, dim3(NH * NB * 32), dim3(256), 0, stream,
                     qu, qv, kb, vv, spt, out);
}